// Round 3
// baseline (339.770 us; speedup 1.0000x reference)
//
#include <hip/hip_runtime.h>

// SMap3x3 — R6: DIAGNOSTIC round. R1's fused kernel (plain stores, fastest
// known) replicated 5x via gridDim.z. All replicas write identical values to
// identical addresses: output is exact, behavior per-block is codegen-identical
// to R1. Purpose:
//   1. dur_us - 228.8 = 4*K  -> direct measurement of kernel time K
//      (disambiguates: K~117us "kernel 3x off roofline" vs K~40us "window is
//      fill/reset-dominated and kernel is already at roofline").
//   2. 5*K > 112us pushes the kernel into the top-5 rocprof rows -> first
//      direct view of its hbm_gbps / VALUBusy / Occupancy / FETCH / WRITE.
// Pre-committed readout table is in the session journal. Next round reverts
// the 5x replication regardless of outcome.

constexpr int H = 480;
constexpr int W = 640;
constexpr int HW = H * W;          // 307200
constexpr int HW4 = HW / 4;        // 76800 float4 per plane
constexpr int BLK = 256;
constexpr int GRIDX = HW4 / BLK;   // 300 (exact)
constexpr int REPS = 5;            // diagnostic replication factor

typedef __attribute__((ext_vector_type(4))) float fvec4;

__device__ __forceinline__ fvec4 nt_load4(const fvec4* p) {
    return __builtin_nontemporal_load(p);
}

__global__ __launch_bounds__(256) void smap3x3_kernel(
    const fvec4* __restrict__ x,
    const fvec4* __restrict__ y,
    const fvec4* __restrict__ z,
    const fvec4* __restrict__ r,
    const fvec4* __restrict__ kq,
    fvec4* __restrict__ out)
{
    // blockIdx.z in [0, REPS) is intentionally unused: replicas do identical
    // work (idempotent stores of identical values -> race-benign, exact).
    const int hw4 = blockIdx.x * BLK + threadIdx.x;  // [0, HW4)
    const int b   = blockIdx.y;                      // [0, 4)
    const size_t pix = (size_t)b * HW4 + hw4;

    // argmin over 9 planes, per component (first-occurrence tie-break: strict <)
    const fvec4* kqb = kq + (size_t)b * 9 * HW4 + hw4;
    fvec4 best = nt_load4(kqb);
    int i0 = 0, i1 = 0, i2 = 0, i3 = 0;
#pragma unroll
    for (int k = 1; k < 9; ++k) {
        const fvec4 kk = nt_load4(kqb + (size_t)k * HW4);
        if (kk.x < best.x) { best.x = kk.x; i0 = k; }
        if (kk.y < best.y) { best.y = kk.y; i1 = k; }
        if (kk.z < best.z) { best.z = kk.z; i2 = k; }
        if (kk.w < best.w) { best.w = kk.w; i3 = k; }
    }

    const fvec4 xv = nt_load4(x + pix);
    const fvec4 yv = nt_load4(y + pix);
    const fvec4 zv = nt_load4(z + pix);
    const fvec4 rv = nt_load4(r + pix);

    // per-component selectors
    int sw0, sw1, sw2, sw3;   // xyz plane selector (-1 = none)
    int s20, s21, s22, s23;   // r plane selector
    { const bool ron = rv.x > 0.5f, zon = zv.x > 0.0f;
      sw0 = ron ? (zon ? i0 : 4) : -1;  s20 = (ron && zon) ? i0 : 4; }
    { const bool ron = rv.y > 0.5f, zon = zv.y > 0.0f;
      sw1 = ron ? (zon ? i1 : 4) : -1;  s21 = (ron && zon) ? i1 : 4; }
    { const bool ron = rv.z > 0.5f, zon = zv.z > 0.0f;
      sw2 = ron ? (zon ? i2 : 4) : -1;  s22 = (ron && zon) ? i2 : 4; }
    { const bool ron = rv.w > 0.5f, zon = zv.w > 0.0f;
      sw3 = ron ? (zon ? i3 : 4) : -1;  s23 = (ron && zon) ? i3 : 4; }

    fvec4* outb = out + (size_t)b * 36 * HW4 + hw4;
#pragma unroll
    for (int k = 0; k < 9; ++k) {
        fvec4 ox, oy, oz, orr;
        const bool m0 = (k == sw0), m1 = (k == sw1), m2 = (k == sw2), m3 = (k == sw3);
        ox.x = m0 ? xv.x : 0.0f;  ox.y = m1 ? xv.y : 0.0f;
        ox.z = m2 ? xv.z : 0.0f;  ox.w = m3 ? xv.w : 0.0f;
        oy.x = m0 ? yv.x : 0.0f;  oy.y = m1 ? yv.y : 0.0f;
        oy.z = m2 ? yv.z : 0.0f;  oy.w = m3 ? yv.w : 0.0f;
        oz.x = m0 ? zv.x : 0.0f;  oz.y = m1 ? zv.y : 0.0f;
        oz.z = m2 ? zv.z : 0.0f;  oz.w = m3 ? zv.w : 0.0f;
        orr.x = (k == s20) ? rv.x : 0.0f;  orr.y = (k == s21) ? rv.y : 0.0f;
        orr.z = (k == s22) ? rv.z : 0.0f;  orr.w = (k == s23) ? rv.w : 0.0f;

        outb[(size_t)(4 * k + 0) * HW4] = ox;
        outb[(size_t)(4 * k + 1) * HW4] = oy;
        outb[(size_t)(4 * k + 2) * HW4] = oz;
        outb[(size_t)(4 * k + 3) * HW4] = orr;
    }
}

extern "C" void kernel_launch(void* const* d_in, const int* in_sizes, int n_in,
                              void* d_out, int out_size, void* d_ws, size_t ws_size,
                              hipStream_t stream) {
    const fvec4* x  = (const fvec4*)d_in[0];
    const fvec4* y  = (const fvec4*)d_in[1];
    const fvec4* z  = (const fvec4*)d_in[2];
    const fvec4* r  = (const fvec4*)d_in[3];
    const fvec4* kq = (const fvec4*)d_in[4];
    fvec4* out = (fvec4*)d_out;

    dim3 grid(GRIDX, 4, REPS);  // 300 x 4 x 5 — 5x idempotent replication
    smap3x3_kernel<<<grid, dim3(BLK), 0, stream>>>(x, y, z, r, kq, out);
}

// Round 4
// 225.351 us; speedup vs baseline: 1.5077x; 1.5077x over previous
//
#include <hip/hip_runtime.h>

// SMap3x3 — R7: revert the R6 5x diagnostic; restore best verified kernel
// (R0 variant: NT loads + NT stores, 227.3 us window).
//
// Closing evidence from the R6 diagnostic (5x idempotent replication):
//   - kernel at saturation runs 6.08-6.10 TB/s mixed (83% write) = 97% of
//     the 6.29 TB/s achievable ceiling; WRITE exactly 5x176.9 MB (no
//     amplification), FETCH shows L3 absorbing re-reads; VALUBusy 9%,
//     occupancy 74%, zero LDS bank conflicts.
//   - window decomposition: harness fixed cost ~168 us (poison fill ~110 us
//     at write ceiling + ~58 us reset dispatches); single-shot kernel
//     ~45-60 us vs 39.5 us traffic floor (240.8 MB @ 6.1 TB/s).
// The kernel's traffic is exact-minimal and its memory path is proven
// clean; remaining gap is <= ~10-20 us buried in fill noise with no
// actionable mechanism (all 4800 waves resident from t=0).
//
// NT stores chosen over plain (tied within noise) because no-allocate
// writes keep the 64 MB of inputs L3-resident across bench iterations.

constexpr int H = 480;
constexpr int W = 640;
constexpr int HW = H * W;          // 307200
constexpr int HW4 = HW / 4;        // 76800 float4 per plane
constexpr int BLK = 256;
constexpr int GRIDX = HW4 / BLK;   // 300 (exact)

typedef __attribute__((ext_vector_type(4))) float fvec4;

__device__ __forceinline__ fvec4 nt_load4(const fvec4* p) {
    return __builtin_nontemporal_load(p);
}
__device__ __forceinline__ void nt_store4(fvec4* p, fvec4 v) {
    __builtin_nontemporal_store(v, p);
}

__global__ __launch_bounds__(256) void smap3x3_kernel(
    const fvec4* __restrict__ x,
    const fvec4* __restrict__ y,
    const fvec4* __restrict__ z,
    const fvec4* __restrict__ r,
    const fvec4* __restrict__ kq,
    fvec4* __restrict__ out)
{
    const int hw4 = blockIdx.x * BLK + threadIdx.x;  // [0, HW4)
    const int b   = blockIdx.y;                      // [0, 4)
    const size_t pix = (size_t)b * HW4 + hw4;

    const fvec4 xv = nt_load4(x + pix);
    const fvec4 yv = nt_load4(y + pix);
    const fvec4 zv = nt_load4(z + pix);
    const fvec4 rv = nt_load4(r + pix);

    // argmin over 9 planes, per component (first-occurrence tie-break: strict <)
    const fvec4* kqb = kq + (size_t)b * 9 * HW4 + hw4;
    fvec4 best = nt_load4(kqb);
    int i0 = 0, i1 = 0, i2 = 0, i3 = 0;
#pragma unroll
    for (int k = 1; k < 9; ++k) {
        const fvec4 kk = nt_load4(kqb + (size_t)k * HW4);
        if (kk.x < best.x) { best.x = kk.x; i0 = k; }
        if (kk.y < best.y) { best.y = kk.y; i1 = k; }
        if (kk.z < best.z) { best.z = kk.z; i2 = k; }
        if (kk.w < best.w) { best.w = kk.w; i3 = k; }
    }

    // per-component selectors
    int sw0, sw1, sw2, sw3;   // xyz plane selector (-1 = none)
    int s20, s21, s22, s23;   // r plane selector
    { const bool ron = rv.x > 0.5f, zon = zv.x > 0.0f;
      sw0 = ron ? (zon ? i0 : 4) : -1;  s20 = (ron && zon) ? i0 : 4; }
    { const bool ron = rv.y > 0.5f, zon = zv.y > 0.0f;
      sw1 = ron ? (zon ? i1 : 4) : -1;  s21 = (ron && zon) ? i1 : 4; }
    { const bool ron = rv.z > 0.5f, zon = zv.z > 0.0f;
      sw2 = ron ? (zon ? i2 : 4) : -1;  s22 = (ron && zon) ? i2 : 4; }
    { const bool ron = rv.w > 0.5f, zon = zv.w > 0.0f;
      sw3 = ron ? (zon ? i3 : 4) : -1;  s23 = (ron && zon) ? i3 : 4; }

    fvec4* outb = out + (size_t)b * 36 * HW4 + hw4;
#pragma unroll
    for (int k = 0; k < 9; ++k) {
        fvec4 ox, oy, oz, orr;
        const bool m0 = (k == sw0), m1 = (k == sw1), m2 = (k == sw2), m3 = (k == sw3);
        ox.x = m0 ? xv.x : 0.0f;  ox.y = m1 ? xv.y : 0.0f;
        ox.z = m2 ? xv.z : 0.0f;  ox.w = m3 ? xv.w : 0.0f;
        oy.x = m0 ? yv.x : 0.0f;  oy.y = m1 ? yv.y : 0.0f;
        oy.z = m2 ? yv.z : 0.0f;  oy.w = m3 ? yv.w : 0.0f;
        oz.x = m0 ? zv.x : 0.0f;  oz.y = m1 ? zv.y : 0.0f;
        oz.z = m2 ? zv.z : 0.0f;  oz.w = m3 ? zv.w : 0.0f;
        orr.x = (k == s20) ? rv.x : 0.0f;  orr.y = (k == s21) ? rv.y : 0.0f;
        orr.z = (k == s22) ? rv.z : 0.0f;  orr.w = (k == s23) ? rv.w : 0.0f;

        nt_store4(outb + (size_t)(4 * k + 0) * HW4, ox);
        nt_store4(outb + (size_t)(4 * k + 1) * HW4, oy);
        nt_store4(outb + (size_t)(4 * k + 2) * HW4, oz);
        nt_store4(outb + (size_t)(4 * k + 3) * HW4, orr);
    }
}

extern "C" void kernel_launch(void* const* d_in, const int* in_sizes, int n_in,
                              void* d_out, int out_size, void* d_ws, size_t ws_size,
                              hipStream_t stream) {
    const fvec4* x  = (const fvec4*)d_in[0];
    const fvec4* y  = (const fvec4*)d_in[1];
    const fvec4* z  = (const fvec4*)d_in[2];
    const fvec4* r  = (const fvec4*)d_in[3];
    const fvec4* kq = (const fvec4*)d_in[4];
    fvec4* out = (fvec4*)d_out;

    dim3 grid(GRIDX, 4);  // 300 x 4 blocks, exact cover
    smap3x3_kernel<<<grid, dim3(BLK), 0, stream>>>(x, y, z, r, kq, out);
}